// Round 7
// baseline (535.403 us; speedup 1.0000x reference)
//
#include <hip/hip_runtime.h>
#include <hip/hip_bf16.h>

#define BB  2048
#define TT  128
#define DD  128
#define HH1 128
#define GG1 512
#define HH2 64
#define GG2 256
#define OO  64

typedef __attribute__((ext_vector_type(8))) short  short8;
typedef __attribute__((ext_vector_type(4))) float  floatx4;

// Pin a value into VGPRs: opaque asm makes rematerializing the load illegal.
#define PIN(x) asm volatile("" : "+v"(x))

// ws byte offsets
#define OFF_WHH1 0            // bf16 [512][128]  gate-permuted rows
#define OFF_WIH1 131072       // bf16 [512][128]  gate-permuted rows
#define OFF_WIH2 262144       // bf16 [256][128]  gate-permuted rows
#define OFF_WHH2 327680       // bf16 [256][64]   gate-permuted rows
#define OFF_B1   360448       // f32 [512] permuted b_ih1+b_hh1
#define OFF_B2   362496       // f32 [256] permuted b_ih2+b_hh2
#define OFF_XBF  524288       // bf16 [2048][128][128]
#define OFF_H1S  67633152     // bf16 [2048][128][128]
// total ~135 MB

__device__ __forceinline__ short f2bf(float f) {
  unsigned u = __float_as_uint(f);
  unsigned r = (u + 0x7FFFu + ((u >> 16) & 1u)) >> 16;
  return (short)r;
}
__device__ __forceinline__ float sigm(float x) {
  return __builtin_amdgcn_rcpf(1.0f + __expf(-x));
}
__device__ __forceinline__ float tanh_fast(float x) {
  return 1.0f - 2.0f * __builtin_amdgcn_rcpf(1.0f + __expf(2.0f * x));
}

// gate permutation: slot p = (cell>>4)*64 + tau*16 + (cell&15)
// => wave wv owns cells [wv*16, wv*16+16), lane's 4 n-tiles = i,f,g,o of ONE cell

// ---------------- prep ----------------
__global__ void k_prep(const float* __restrict__ wih1, const float* __restrict__ whh1,
                       const float* __restrict__ bih1, const float* __restrict__ bhh1,
                       const float* __restrict__ wih2, const float* __restrict__ whh2,
                       const float* __restrict__ bih2, const float* __restrict__ bhh2,
                       char* __restrict__ ws) {
  short* WHH1 = (short*)(ws + OFF_WHH1);
  short* WIH1 = (short*)(ws + OFF_WIH1);
  short* WIH2 = (short*)(ws + OFF_WIH2);
  short* WHH2 = (short*)(ws + OFF_WHH2);
  float* B1 = (float*)(ws + OFF_B1);
  float* B2 = (float*)(ws + OFF_B2);
  int idx = blockIdx.x * blockDim.x + threadIdx.x;
  int stride = gridDim.x * blockDim.x;
  for (int i = idx; i < GG1 * DD; i += stride) {
    int g = i >> 7, k = i & 127;
    int tau = g >> 7, j = g & 127;
    int p = ((j >> 4) << 6) + (tau << 4) + (j & 15);
    WIH1[p * DD + k] = f2bf(wih1[i]);
    WHH1[p * HH1 + k] = f2bf(whh1[i]);
  }
  for (int i = idx; i < GG2 * HH1; i += stride) {
    int g = i >> 7, k = i & 127;
    int tau = g >> 6, j = g & 63;
    int p = ((j >> 4) << 6) + (tau << 4) + (j & 15);
    WIH2[p * HH1 + k] = f2bf(wih2[i]);
  }
  for (int i = idx; i < GG2 * HH2; i += stride) {
    int g = i >> 6, k = i & 63;
    int tau = g >> 6, j = g & 63;
    int p = ((j >> 4) << 6) + (tau << 4) + (j & 15);
    WHH2[p * HH2 + k] = f2bf(whh2[i]);
  }
  for (int g = idx; g < GG1; g += stride) {
    int tau = g >> 7, j = g & 127;
    int p = ((j >> 4) << 6) + (tau << 4) + (j & 15);
    B1[p] = bih1[g] + bhh1[g];
  }
  for (int g = idx; g < GG2; g += stride) {
    int tau = g >> 6, j = g & 63;
    int p = ((j >> 4) << 6) + (tau << 4) + (j & 15);
    B2[p] = bih2[g] + bhh2[g];
  }
}

// ---------------- xcast ----------------
__global__ __launch_bounds__(256) void k_xcast(const float* __restrict__ x,
                                               short* __restrict__ xbf) {
  size_t i = ((size_t)blockIdx.x * 256 + threadIdx.x) * 8;
  float4 a = *(const float4*)&x[i];
  float4 b = *(const float4*)&x[i + 4];
  short8 o;
  o[0] = f2bf(a.x); o[1] = f2bf(a.y); o[2] = f2bf(a.z); o[3] = f2bf(a.w);
  o[4] = f2bf(b.x); o[5] = f2bf(b.y); o[6] = f2bf(b.z); o[7] = f2bf(b.w);
  *(short8*)&xbf[i] = o;
}

// ---------------- rec1f: 8 rows/block, grid 256, in-register cell update ----------------
__global__ __launch_bounds__(512, 2) void k_rec1f(const char* __restrict__ ws,
                                                  short* __restrict__ h1s) {
  __shared__ short hb0[16 * 136];     // double-buffered bf16 h (rows 8..15 stay 0)
  __shared__ short hb1[16 * 136];
  const short* WHH = (const short*)(ws + OFF_WHH1);
  const short* WIH = (const short*)(ws + OFF_WIH1);
  const short* XBF = (const short*)(ws + OFF_XBF);
  const float* B1 = (const float*)(ws + OFF_B1);
  const int lane = threadIdx.x & 63;
  const int wv = threadIdx.x >> 6;          // 0..7
  const int col = lane & 15, quad = lane >> 4;
  const int n0 = wv * 64;
  const int r0 = blockIdx.x * 8;
  const int cellj = wv * 16 + col;          // this lane's cell column

  short8 wh[4][4], wx[4][4];
#pragma unroll
  for (int nt = 0; nt < 4; ++nt)
#pragma unroll
    for (int kk = 0; kk < 4; ++kk) {
      wh[nt][kk] = *(const short8*)&WHH[(n0 + nt * 16 + col) * HH1 + kk * 32 + quad * 8];
      wx[nt][kk] = *(const short8*)&WIH[(n0 + nt * 16 + col) * DD + kk * 32 + quad * 8];
      PIN(wh[nt][kk]);
      PIN(wx[nt][kk]);
    }
  float bias[4];
#pragma unroll
  for (int nt = 0; nt < 4; ++nt) bias[nt] = B1[n0 + nt * 16 + col];

  for (int i = threadIdx.x; i < 16 * 136; i += 512) { hb0[i] = 0; hb1[i] = 0; }

  const bool aload = (col < 8);
  const short* xbase = XBF + (size_t)(r0 + (col & 7)) * TT * DD;
  short8 ax_a[4], ax_b[4];
#pragma unroll
  for (int kk = 0; kk < 4; ++kk) {
    short8 z = {0, 0, 0, 0, 0, 0, 0, 0};
    ax_a[kk] = aload ? *(const short8*)&xbase[kk * 32 + quad * 8] : z;
    ax_b[kk] = z;
  }

  float cst[4] = {0.f, 0.f, 0.f, 0.f};      // cell state, rows quad*4+r (quad<2 real)
  __syncthreads();

  auto step = [&](int t, short8 (&axu)[4], short8 (&axp)[4],
                  const short* rb, short* wb, bool dopf) {
    if (dopf && aload) {
#pragma unroll
      for (int kk = 0; kk < 4; ++kk)
        axp[kk] = *(const short8*)&xbase[(t + 1) * DD + kk * 32 + quad * 8];
    }
    short8 ah[4];
#pragma unroll
    for (int kk = 0; kk < 4; ++kk)
      ah[kk] = *(const short8*)&rb[col * 136 + kk * 32 + quad * 8];
    floatx4 acc[4];
#pragma unroll
    for (int nt = 0; nt < 4; ++nt)
      acc[nt] = (floatx4){bias[nt], bias[nt], bias[nt], bias[nt]};
#pragma unroll
    for (int kk = 0; kk < 4; ++kk)
#pragma unroll
      for (int nt = 0; nt < 4; ++nt)
        acc[nt] = __builtin_amdgcn_mfma_f32_16x16x32_bf16(axu[kk], wx[nt][kk], acc[nt], 0, 0, 0);
#pragma unroll
    for (int kk = 0; kk < 4; ++kk)
#pragma unroll
      for (int nt = 0; nt < 4; ++nt)
        acc[nt] = __builtin_amdgcn_mfma_f32_16x16x32_bf16(ah[kk], wh[nt][kk], acc[nt], 0, 0, 0);

    if (quad < 2) {                   // rows 0..7 real; all 4 gates in-lane
#pragma unroll
      for (int r = 0; r < 4; ++r) {
        int row = quad * 4 + r;
        float pi = acc[0][r], pf = acc[1][r], pg = acc[2][r], po = acc[3][r];
        cst[r] = fmaf(sigm(pf), cst[r], sigm(pi) * tanh_fast(pg));
        float hh = sigm(po) * tanh_fast(cst[r]);
        short hbv = f2bf(hh);
        wb[row * 136 + cellj] = hbv;
        h1s[((size_t)(r0 + row) * TT + t) * HH1 + cellj] = hbv;
      }
    }
    __syncthreads();
  };

  for (int t = 0; t < TT; t += 2) {
    step(t,     ax_a, ax_b, hb0, hb1, true);
    step(t + 1, ax_b, ax_a, hb1, hb0, t + 2 < TT);
  }
}

// ---------------- rec2f: 4 rows/block, grid 512, in-register cell update + dense ----------------
__global__ __launch_bounds__(256, 2) void k_rec2f(const char* __restrict__ ws,
                                                  const short* __restrict__ h1s,
                                                  const float* __restrict__ wd,
                                                  const float* __restrict__ bd,
                                                  float* __restrict__ out) {
  __shared__ short hb0[16 * 72];      // rows 4..15 stay 0
  __shared__ short hb1[16 * 72];
  __shared__ float h2f[4 * HH2];
  const short* WHH = (const short*)(ws + OFF_WHH2);
  const short* WIH = (const short*)(ws + OFF_WIH2);
  const float* B2 = (const float*)(ws + OFF_B2);
  const int lane = threadIdx.x & 63;
  const int wv = threadIdx.x >> 6;    // 0..3
  const int col = lane & 15, quad = lane >> 4;
  const int n0 = wv * 64;
  const int r0 = blockIdx.x * 4;
  const int cellj = wv * 16 + col;    // 0..63

  short8 wh[4][2], wx[4][4];
#pragma unroll
  for (int nt = 0; nt < 4; ++nt) {
#pragma unroll
    for (int kk = 0; kk < 2; ++kk) {
      wh[nt][kk] = *(const short8*)&WHH[(n0 + nt * 16 + col) * HH2 + kk * 32 + quad * 8];
      PIN(wh[nt][kk]);
    }
#pragma unroll
    for (int kk = 0; kk < 4; ++kk) {
      wx[nt][kk] = *(const short8*)&WIH[(n0 + nt * 16 + col) * HH1 + kk * 32 + quad * 8];
      PIN(wx[nt][kk]);
    }
  }
  float bias[4];
#pragma unroll
  for (int nt = 0; nt < 4; ++nt) bias[nt] = B2[n0 + nt * 16 + col];

  for (int i = threadIdx.x; i < 16 * 72; i += 256) { hb0[i] = 0; hb1[i] = 0; }

  const bool aload = (col < 4);
  const short* h1base = h1s + (size_t)(r0 + (col & 3)) * TT * HH1;
  short8 ax_a[4], ax_b[4];
#pragma unroll
  for (int kk = 0; kk < 4; ++kk) {
    short8 z = {0, 0, 0, 0, 0, 0, 0, 0};
    ax_a[kk] = aload ? *(const short8*)&h1base[kk * 32 + quad * 8] : z;
    ax_b[kk] = z;
  }

  float cst[4] = {0.f, 0.f, 0.f, 0.f};  // rows 0..3 (quad==0 real)
  __syncthreads();

  auto step = [&](int t, short8 (&axu)[4], short8 (&axp)[4],
                  const short* rb, short* wb, bool dopf) {
    if (dopf && aload) {
#pragma unroll
      for (int kk = 0; kk < 4; ++kk)
        axp[kk] = *(const short8*)&h1base[(t + 1) * HH1 + kk * 32 + quad * 8];
    }
    short8 ah[2];
#pragma unroll
    for (int kk = 0; kk < 2; ++kk)
      ah[kk] = *(const short8*)&rb[col * 72 + kk * 32 + quad * 8];
    floatx4 acc[4];
#pragma unroll
    for (int nt = 0; nt < 4; ++nt)
      acc[nt] = (floatx4){bias[nt], bias[nt], bias[nt], bias[nt]};
#pragma unroll
    for (int kk = 0; kk < 4; ++kk)
#pragma unroll
      for (int nt = 0; nt < 4; ++nt)
        acc[nt] = __builtin_amdgcn_mfma_f32_16x16x32_bf16(axu[kk], wx[nt][kk], acc[nt], 0, 0, 0);
#pragma unroll
    for (int kk = 0; kk < 2; ++kk)
#pragma unroll
      for (int nt = 0; nt < 4; ++nt)
        acc[nt] = __builtin_amdgcn_mfma_f32_16x16x32_bf16(ah[kk], wh[nt][kk], acc[nt], 0, 0, 0);

    if (quad == 0) {                  // rows 0..3 real
#pragma unroll
      for (int r = 0; r < 4; ++r) {
        float pi = acc[0][r], pf = acc[1][r], pg = acc[2][r], po = acc[3][r];
        cst[r] = fmaf(sigm(pf), cst[r], sigm(pi) * tanh_fast(pg));
        float hh = sigm(po) * tanh_fast(cst[r]);
        wb[r * 72 + cellj] = f2bf(hh);
        if (t == TT - 1) h2f[r * HH2 + cellj] = hh;
      }
    }
    __syncthreads();
  };

  for (int t = 0; t < TT; t += 2) {
    step(t,     ax_a, ax_b, hb0, hb1, true);
    step(t + 1, ax_b, ax_a, hb1, hb0, t + 2 < TT);
  }

  // dense head (fp32)
  {
    const int o = threadIdx.x & 63;
    const int r = threadIdx.x >> 6;   // 0..3
    float acc = bd[o];
    for (int k = 0; k < HH2; ++k)
      acc = fmaf(h2f[r * HH2 + k], wd[o * HH2 + k], acc);
    out[(size_t)(r0 + r) * OO + o] = fmaxf(acc, 0.f);
  }
}

extern "C" void kernel_launch(void* const* d_in, const int* in_sizes, int n_in,
                              void* d_out, int out_size, void* d_ws, size_t ws_size,
                              hipStream_t stream) {
  const float* x       = (const float*)d_in[0];
  const float* w_ih1   = (const float*)d_in[1];
  const float* w_hh1   = (const float*)d_in[2];
  const float* b_ih1   = (const float*)d_in[3];
  const float* b_hh1   = (const float*)d_in[4];
  const float* w_ih2   = (const float*)d_in[5];
  const float* w_hh2   = (const float*)d_in[6];
  const float* b_ih2   = (const float*)d_in[7];
  const float* b_hh2   = (const float*)d_in[8];
  const float* w_dense = (const float*)d_in[9];
  const float* b_dense = (const float*)d_in[10];
  char* ws = (char*)d_ws;
  short* xbf = (short*)(ws + OFF_XBF);
  short* h1s = (short*)(ws + OFF_H1S);
  float* out = (float*)d_out;

  hipLaunchKernelGGL(k_prep, dim3(256), dim3(256), 0, stream,
                     w_ih1, w_hh1, b_ih1, b_hh1, w_ih2, w_hh2, b_ih2, b_hh2, ws);
  hipLaunchKernelGGL(k_xcast, dim3((BB * TT * DD) / (256 * 8)), dim3(256), 0, stream, x, xbf);
  hipLaunchKernelGGL(k_rec1f, dim3(BB / 8), dim3(512), 0, stream, ws, h1s);
  hipLaunchKernelGGL(k_rec2f, dim3(BB / 4), dim3(256), 0, stream, ws, h1s, w_dense, b_dense, out);
}

// Round 8
// 496.020 us; speedup vs baseline: 1.0794x; 1.0794x over previous
//
#include <hip/hip_runtime.h>
#include <hip/hip_bf16.h>

#define BB  2048
#define TT  128
#define DD  128
#define HH1 128
#define GG1 512
#define HH2 64
#define GG2 256
#define OO  64

typedef __attribute__((ext_vector_type(8))) short  short8;
typedef __attribute__((ext_vector_type(4))) float  floatx4;

// Pin a value into VGPRs: opaque asm makes rematerializing the load illegal.
#define PIN(x) asm volatile("" : "+v"(x))
// Barrier that waits LDS ops only — does NOT drain vmcnt, so global prefetch
// loads stay in flight across it and h1s stores retire asynchronously.
#define BAR() __asm__ volatile("s_waitcnt lgkmcnt(0)\n\ts_barrier" ::: "memory")

// ws byte offsets
#define OFF_WHH1 0            // bf16 [512][128]
#define OFF_WIH1 131072       // bf16 [512][128]
#define OFF_WIH2 262144       // bf16 [256][128]
#define OFF_WHH2 327680       // bf16 [256][64]
#define OFF_B1   360448       // f32 [512]  b_ih1+b_hh1
#define OFF_B2   362496       // f32 [256]  b_ih2+b_hh2
#define OFF_XBF  524288       // bf16 [2048][128][128]
#define OFF_H1S  67633152     // bf16 [2048][128][128]
// total ~135 MB

__device__ __forceinline__ short f2bf(float f) {
  unsigned u = __float_as_uint(f);
  unsigned r = (u + 0x7FFFu + ((u >> 16) & 1u)) >> 16;
  return (short)r;
}
__device__ __forceinline__ float sigm(float x) {
  return __builtin_amdgcn_rcpf(1.0f + __expf(-x));
}
__device__ __forceinline__ float tanh_fast(float x) {
  return 1.0f - 2.0f * __builtin_amdgcn_rcpf(1.0f + __expf(2.0f * x));
}

// ---------------- prep: bf16 weight conversion + combined biases ----------------
__global__ void k_prep(const float* __restrict__ wih1, const float* __restrict__ whh1,
                       const float* __restrict__ bih1, const float* __restrict__ bhh1,
                       const float* __restrict__ wih2, const float* __restrict__ whh2,
                       const float* __restrict__ bih2, const float* __restrict__ bhh2,
                       char* __restrict__ ws) {
  short* WHH1 = (short*)(ws + OFF_WHH1);
  short* WIH1 = (short*)(ws + OFF_WIH1);
  short* WIH2 = (short*)(ws + OFF_WIH2);
  short* WHH2 = (short*)(ws + OFF_WHH2);
  float* B1 = (float*)(ws + OFF_B1);
  float* B2 = (float*)(ws + OFF_B2);
  int idx = blockIdx.x * blockDim.x + threadIdx.x;
  int stride = gridDim.x * blockDim.x;
  for (int i = idx; i < GG1 * DD; i += stride) { WIH1[i] = f2bf(wih1[i]); WHH1[i] = f2bf(whh1[i]); }
  for (int i = idx; i < GG2 * HH1; i += stride) WIH2[i] = f2bf(wih2[i]);
  for (int i = idx; i < GG2 * HH2; i += stride) WHH2[i] = f2bf(whh2[i]);
  for (int i = idx; i < GG1; i += stride) B1[i] = bih1[i] + bhh1[i];
  for (int i = idx; i < GG2; i += stride) B2[i] = bih2[i] + bhh2[i];
}

// ---------------- xcast ----------------
__global__ __launch_bounds__(256) void k_xcast(const float* __restrict__ x,
                                               short* __restrict__ xbf) {
  size_t i = ((size_t)blockIdx.x * 256 + threadIdx.x) * 8;
  float4 a = *(const float4*)&x[i];
  float4 b = *(const float4*)&x[i + 4];
  short8 o;
  o[0] = f2bf(a.x); o[1] = f2bf(a.y); o[2] = f2bf(a.z); o[3] = f2bf(a.w);
  o[4] = f2bf(b.x); o[5] = f2bf(b.y); o[6] = f2bf(b.z); o[7] = f2bf(b.w);
  *(short8*)&xbf[i] = o;
}

// ---------------- rec1f: 8 rows/block, grid 256; gsm exchange; lgkm-only barriers ----------------
__global__ __launch_bounds__(512, 2) void k_rec1f(const char* __restrict__ ws,
                                                  short* __restrict__ h1s) {
  __shared__ short hb0[16 * 136];     // bf16 h double buffer (rows 8..15 stay 0)
  __shared__ short hb1[16 * 136];
  __shared__ float gsm[8 * 516];      // raw preacts, padded stride
  const short* WHH = (const short*)(ws + OFF_WHH1);
  const short* WIH = (const short*)(ws + OFF_WIH1);
  const short* XBF = (const short*)(ws + OFF_XBF);
  const float* B1 = (const float*)(ws + OFF_B1);
  const int lane = threadIdx.x & 63;
  const int wv = threadIdx.x >> 6;          // 0..7
  const int col = lane & 15, quad = lane >> 4;
  const int n0 = wv * 64;
  const int r0 = blockIdx.x * 8;

  short8 wh[4][4], wx[4][4];
#pragma unroll
  for (int nt = 0; nt < 4; ++nt)
#pragma unroll
    for (int kk = 0; kk < 4; ++kk) {
      wh[nt][kk] = *(const short8*)&WHH[(n0 + nt * 16 + col) * HH1 + kk * 32 + quad * 8];
      wx[nt][kk] = *(const short8*)&WIH[(n0 + nt * 16 + col) * DD + kk * 32 + quad * 8];
      PIN(wh[nt][kk]);
      PIN(wx[nt][kk]);
    }
  float bias[4];
#pragma unroll
  for (int nt = 0; nt < 4; ++nt) bias[nt] = B1[n0 + nt * 16 + col];

  for (int i = threadIdx.x; i < 16 * 136; i += 512) { hb0[i] = 0; hb1[i] = 0; }

  const bool aload = (col < 8);
  const short* xbase = XBF + (size_t)(r0 + (col & 7)) * TT * DD;
  short8 ax_a[4], ax_b[4];
#pragma unroll
  for (int kk = 0; kk < 4; ++kk) {
    short8 z = {0, 0, 0, 0, 0, 0, 0, 0};
    ax_a[kk] = aload ? *(const short8*)&xbase[kk * 32 + quad * 8] : z;
    ax_b[kk] = z;
  }

  const int j = threadIdx.x & 127;    // cell col
  const int rr = threadIdx.x >> 7;    // cell rows rr, rr+4
  float cA = 0.f, cB = 0.f;
  __syncthreads();                    // one-time full barrier after init

  auto step = [&](int t, short8 (&axu)[4], short8 (&axp)[4],
                  const short* rb, short* wb, bool dopf) {
    // issue LDS fragment reads first (latency overlaps x-MFMAs)
    short8 ah[4];
#pragma unroll
    for (int kk = 0; kk < 4; ++kk)
      ah[kk] = *(const short8*)&rb[col * 136 + kk * 32 + quad * 8];
    // prefetch x(t+1): stays in flight across both barriers (lgkm-only)
    if (dopf && aload) {
#pragma unroll
      for (int kk = 0; kk < 4; ++kk)
        axp[kk] = *(const short8*)&xbase[(t + 1) * DD + kk * 32 + quad * 8];
    }
    floatx4 acc[4];
#pragma unroll
    for (int nt = 0; nt < 4; ++nt)
      acc[nt] = (floatx4){bias[nt], bias[nt], bias[nt], bias[nt]};
#pragma unroll
    for (int kk = 0; kk < 4; ++kk)
#pragma unroll
      for (int nt = 0; nt < 4; ++nt)
        acc[nt] = __builtin_amdgcn_mfma_f32_16x16x32_bf16(axu[kk], wx[nt][kk], acc[nt], 0, 0, 0);
#pragma unroll
    for (int kk = 0; kk < 4; ++kk)
#pragma unroll
      for (int nt = 0; nt < 4; ++nt)
        acc[nt] = __builtin_amdgcn_mfma_f32_16x16x32_bf16(ah[kk], wh[nt][kk], acc[nt], 0, 0, 0);

    if (quad < 2) {                   // rows 0..7 real
#pragma unroll
      for (int nt = 0; nt < 4; ++nt)
#pragma unroll
        for (int r = 0; r < 4; ++r)
          gsm[(quad * 4 + r) * 516 + n0 + nt * 16 + col] = acc[nt][r];
    }
    BAR();

    {
      float i0 = gsm[rr * 516 + j],       f0 = gsm[rr * 516 + 128 + j];
      float g0 = gsm[rr * 516 + 256 + j], o0 = gsm[rr * 516 + 384 + j];
      cA = fmaf(sigm(f0), cA, sigm(i0) * tanh_fast(g0));
      float hA = sigm(o0) * tanh_fast(cA);
      int r2 = rr + 4;
      float i1 = gsm[r2 * 516 + j],       f1 = gsm[r2 * 516 + 128 + j];
      float g1 = gsm[r2 * 516 + 256 + j], o1 = gsm[r2 * 516 + 384 + j];
      cB = fmaf(sigm(f1), cB, sigm(i1) * tanh_fast(g1));
      float hB = sigm(o1) * tanh_fast(cB);
      short ha = f2bf(hA), hb = f2bf(hB);
      wb[rr * 136 + j] = ha;
      wb[r2 * 136 + j] = hb;
      // global stores: never drained by a barrier, retire asynchronously
      h1s[((size_t)(r0 + rr) * TT + t) * HH1 + j] = ha;
      h1s[((size_t)(r0 + r2) * TT + t) * HH1 + j] = hb;
    }
    BAR();
  };

  for (int t = 0; t < TT; t += 2) {
    step(t,     ax_a, ax_b, hb0, hb1, true);
    step(t + 1, ax_b, ax_a, hb1, hb0, t + 2 < TT);
  }
}

// ---------------- rec2f: 4 rows/block, grid 512; same structure + dense head ----------------
__global__ __launch_bounds__(256, 2) void k_rec2f(const char* __restrict__ ws,
                                                  const short* __restrict__ h1s,
                                                  const float* __restrict__ wd,
                                                  const float* __restrict__ bd,
                                                  float* __restrict__ out) {
  __shared__ short hb0[16 * 72];      // rows 4..15 stay 0
  __shared__ short hb1[16 * 72];
  __shared__ float gsm[4 * 260];
  __shared__ float h2f[4 * HH2];
  const short* WHH = (const short*)(ws + OFF_WHH2);
  const short* WIH = (const short*)(ws + OFF_WIH2);
  const float* B2 = (const float*)(ws + OFF_B2);
  const int lane = threadIdx.x & 63;
  const int wv = threadIdx.x >> 6;    // 0..3
  const int col = lane & 15, quad = lane >> 4;
  const int n0 = wv * 64;
  const int r0 = blockIdx.x * 4;

  short8 wh[4][2], wx[4][4];
#pragma unroll
  for (int nt = 0; nt < 4; ++nt) {
#pragma unroll
    for (int kk = 0; kk < 2; ++kk) {
      wh[nt][kk] = *(const short8*)&WHH[(n0 + nt * 16 + col) * HH2 + kk * 32 + quad * 8];
      PIN(wh[nt][kk]);
    }
#pragma unroll
    for (int kk = 0; kk < 4; ++kk) {
      wx[nt][kk] = *(const short8*)&WIH[(n0 + nt * 16 + col) * HH1 + kk * 32 + quad * 8];
      PIN(wx[nt][kk]);
    }
  }
  float bias[4];
#pragma unroll
  for (int nt = 0; nt < 4; ++nt) bias[nt] = B2[n0 + nt * 16 + col];

  for (int i = threadIdx.x; i < 16 * 72; i += 256) { hb0[i] = 0; hb1[i] = 0; }

  const bool aload = (col < 4);
  const short* h1base = h1s + (size_t)(r0 + (col & 3)) * TT * HH1;
  short8 ax_a[4], ax_b[4];
#pragma unroll
  for (int kk = 0; kk < 4; ++kk) {
    short8 z = {0, 0, 0, 0, 0, 0, 0, 0};
    ax_a[kk] = aload ? *(const short8*)&h1base[kk * 32 + quad * 8] : z;
    ax_b[kk] = z;
  }

  const int j = threadIdx.x & 63;     // cell col
  const int rr = threadIdx.x >> 6;    // cell row 0..3 (1 cell/thread)
  float cc = 0.f;
  __syncthreads();

  auto step = [&](int t, short8 (&axu)[4], short8 (&axp)[4],
                  const short* rb, short* wb, bool dopf) {
    short8 ah[2];
#pragma unroll
    for (int kk = 0; kk < 2; ++kk)
      ah[kk] = *(const short8*)&rb[col * 72 + kk * 32 + quad * 8];
    if (dopf && aload) {
#pragma unroll
      for (int kk = 0; kk < 4; ++kk)
        axp[kk] = *(const short8*)&h1base[(t + 1) * HH1 + kk * 32 + quad * 8];
    }
    floatx4 acc[4];
#pragma unroll
    for (int nt = 0; nt < 4; ++nt)
      acc[nt] = (floatx4){bias[nt], bias[nt], bias[nt], bias[nt]};
#pragma unroll
    for (int kk = 0; kk < 4; ++kk)
#pragma unroll
      for (int nt = 0; nt < 4; ++nt)
        acc[nt] = __builtin_amdgcn_mfma_f32_16x16x32_bf16(axu[kk], wx[nt][kk], acc[nt], 0, 0, 0);
#pragma unroll
    for (int kk = 0; kk < 2; ++kk)
#pragma unroll
      for (int nt = 0; nt < 4; ++nt)
        acc[nt] = __builtin_amdgcn_mfma_f32_16x16x32_bf16(ah[kk], wh[nt][kk], acc[nt], 0, 0, 0);

    if (quad == 0) {                  // rows 0..3 real
#pragma unroll
      for (int nt = 0; nt < 4; ++nt)
#pragma unroll
        for (int r = 0; r < 4; ++r)
          gsm[r * 260 + n0 + nt * 16 + col] = acc[nt][r];
    }
    BAR();

    {
      float i0 = gsm[rr * 260 + j],      f0 = gsm[rr * 260 + 64 + j];
      float g0 = gsm[rr * 260 + 128 + j], o0 = gsm[rr * 260 + 192 + j];
      cc = fmaf(sigm(f0), cc, sigm(i0) * tanh_fast(g0));
      float hh = sigm(o0) * tanh_fast(cc);
      wb[rr * 72 + j] = f2bf(hh);
      if (t == TT - 1) h2f[rr * HH2 + j] = hh;
    }
    BAR();
  };

  for (int t = 0; t < TT; t += 2) {
    step(t,     ax_a, ax_b, hb0, hb1, true);
    step(t + 1, ax_b, ax_a, hb1, hb0, t + 2 < TT);
  }

  // dense head (fp32); h2f complete after final BAR
  {
    const int o = threadIdx.x & 63;
    const int r = threadIdx.x >> 6;   // 0..3
    float acc = bd[o];
    for (int k = 0; k < HH2; ++k)
      acc = fmaf(h2f[r * HH2 + k], wd[o * HH2 + k], acc);
    out[(size_t)(r0 + r) * OO + o] = fmaxf(acc, 0.f);
  }
}

extern "C" void kernel_launch(void* const* d_in, const int* in_sizes, int n_in,
                              void* d_out, int out_size, void* d_ws, size_t ws_size,
                              hipStream_t stream) {
  const float* x       = (const float*)d_in[0];
  const float* w_ih1   = (const float*)d_in[1];
  const float* w_hh1   = (const float*)d_in[2];
  const float* b_ih1   = (const float*)d_in[3];
  const float* b_hh1   = (const float*)d_in[4];
  const float* w_ih2   = (const float*)d_in[5];
  const float* w_hh2   = (const float*)d_in[6];
  const float* b_ih2   = (const float*)d_in[7];
  const float* b_hh2   = (const float*)d_in[8];
  const float* w_dense = (const float*)d_in[9];
  const float* b_dense = (const float*)d_in[10];
  char* ws = (char*)d_ws;
  short* xbf = (short*)(ws + OFF_XBF);
  short* h1s = (short*)(ws + OFF_H1S);
  float* out = (float*)d_out;

  hipLaunchKernelGGL(k_prep, dim3(256), dim3(256), 0, stream,
                     w_ih1, w_hh1, b_ih1, b_hh1, w_ih2, w_hh2, b_ih2, b_hh2, ws);
  hipLaunchKernelGGL(k_xcast, dim3((BB * TT * DD) / (256 * 8)), dim3(256), 0, stream, x, xbf);
  hipLaunchKernelGGL(k_rec1f, dim3(BB / 8), dim3(512), 0, stream, ws, h1s);
  hipLaunchKernelGGL(k_rec2f, dim3(BB / 4), dim3(256), 0, stream, ws, h1s, w_dense, b_dense, out);
}